// Round 1
// baseline (163.501 us; speedup 1.0000x reference)
//
#include <hip/hip_runtime.h>

#define N_PAIR 3840
#define N_BOX 2176

typedef short bf16x8 __attribute__((ext_vector_type(8)));
typedef float f32x4 __attribute__((ext_vector_type(4)));

static __device__ __forceinline__ ushort f2bf(float f) {
    uint x = __float_as_uint(f);
    uint r = (x + 0x7FFFu + ((x >> 16) & 1u)) >> 16;
    return (ushort)r;
}
static __device__ __forceinline__ float bf2f(ushort u) {
    return __uint_as_float(((uint)u) << 16);
}

// ---------------- transpose + convert: in (K,N) f32 -> out (N,Kpad) bf16, zero-padded
__global__ void transpose_convert(const float* __restrict__ in0,
                                  const float* __restrict__ in1,
                                  const float* __restrict__ in2,
                                  ushort* __restrict__ out,
                                  int K, int N, int Kpad) {
    const float* in = (blockIdx.z == 0) ? in0 : (blockIdx.z == 1 ? in1 : in2);
    ushort* o = out + (size_t)blockIdx.z * N * Kpad;
    __shared__ float tile[64][65];
    int k0 = blockIdx.x * 64, n0 = blockIdx.y * 64;
    int t = threadIdx.x;
    int r = t >> 2, c4 = (t & 3) * 16;
#pragma unroll
    for (int i = 0; i < 16; i++) {
        int k = k0 + r, n = n0 + c4 + i;
        tile[r][c4 + i] = (k < K && n < N) ? in[(size_t)k * N + n] : 0.f;
    }
    __syncthreads();
#pragma unroll
    for (int i = 0; i < 16; i++) {
        int n = n0 + r, k = k0 + c4 + i;
        if (n < N && k < Kpad) o[(size_t)n * Kpad + k] = f2bf(tile[c4 + i][r]);
    }
}

// ---------------- box geometry features -> hin cols [256, 288)
__global__ void loc_kernel(const float* __restrict__ boxes,
                           const float* __restrict__ im_info,
                           const int* __restrict__ o1, const int* __restrict__ o2,
                           const int* __restrict__ u, const int* __restrict__ im,
                           ushort* __restrict__ hin) {
    int p = blockIdx.x * blockDim.x + threadIdx.x;
    if (p >= N_PAIR) return;
    const float* sb = boxes + 5 * o1[p] + 1;
    const float* ob = boxes + 5 * o2[p] + 1;
    const float* ub = boxes + 5 * u[p] + 1;
    const float* ii = im_info + 3 * im[p];
    float hi = ii[0], wi = ii[1];
    float sx1 = sb[0], sy1 = sb[1], sx2 = sb[2], sy2 = sb[3];
    float ox1 = ob[0], oy1 = ob[1], ox2 = ob[2], oy2 = ob[3];
    float ux1 = ub[0], uy1 = ub[1], ux2 = ub[2], uy2 = ub[3];
    float x_s = (sx1 + sx2) * 0.5f, y_s = (sy1 + sy2) * 0.5f;
    float w_s = sx2 - sx1, h_s = sy2 - sy1;
    float x_o = (ox1 + ox2) * 0.5f, y_o = (oy1 + oy2) * 0.5f;
    float w_o = ox2 - ox1, h_o = oy2 - oy1;
    float a_s = w_s * h_s, a_o = w_o * h_o;
    float a_u = (ux2 - ux1) * (uy2 - uy1);
    float area = wi * hi;
    float f[19];
    f[0] = x_s / wi;            f[1] = y_s / hi;
    f[2] = (x_s + w_s) / wi;    f[3] = (y_s + h_s) / hi;
    f[4] = a_s / area;
    f[5] = x_o / wi;            f[6] = y_o / hi;
    f[7] = (x_o + w_o) / wi;    f[8] = (y_o + h_o) / hi;
    f[9] = a_o / area;
    f[10] = (x_s - x_o) / w_o;  f[11] = (y_s - y_o) / h_o;
    f[12] = logf(w_s / w_o);    f[13] = logf(h_s / h_o);
    f[14] = (x_o - x_s) / w_s;  f[15] = (y_o - y_s) / h_s;
    f[16] = logf(w_o / w_s);    f[17] = logf(h_o / h_s);
    f[18] = a_u / area;
    ushort* row = hin + (size_t)p * 288 + 256;
#pragma unroll
    for (int i = 0; i < 19; i++) row[i] = f2bf(f[i]);
#pragma unroll
    for (int i = 19; i < 32; i++) row[i] = 0;
}

// ---------------- LDS staging helpers (BK=64 tiles, 128 rows, XOR swizzle)
__device__ __forceinline__ void stage_f32(const float* __restrict__ src, int ld,
                                          ushort* __restrict__ lds, int t) {
#pragma unroll
    for (int it = 0; it < 4; ++it) {
        int e = (it * 256 + t) * 8;
        int row = e >> 6, col = e & 63;
        const float4* g = reinterpret_cast<const float4*>(src + (size_t)row * ld + col);
        float4 v0 = g[0];
        float4 v1 = g[1];
        union { bf16x8 v; ushort us[8]; } pk;
        pk.us[0] = f2bf(v0.x); pk.us[1] = f2bf(v0.y); pk.us[2] = f2bf(v0.z); pk.us[3] = f2bf(v0.w);
        pk.us[4] = f2bf(v1.x); pk.us[5] = f2bf(v1.y); pk.us[6] = f2bf(v1.z); pk.us[7] = f2bf(v1.w);
        int off = (row << 7) + ((col << 1) ^ ((row & 7) << 4));
        *reinterpret_cast<bf16x8*>(reinterpret_cast<char*>(lds) + off) = pk.v;
    }
}
__device__ __forceinline__ void stage_bf16(const ushort* __restrict__ src, int ld,
                                           ushort* __restrict__ lds, int t) {
#pragma unroll
    for (int it = 0; it < 4; ++it) {
        int e = (it * 256 + t) * 8;
        int row = e >> 6, col = e & 63;
        bf16x8 v = *reinterpret_cast<const bf16x8*>(src + (size_t)row * ld + col);
        int off = (row << 7) + ((col << 1) ^ ((row & 7) << 4));
        *reinterpret_cast<bf16x8*>(reinterpret_cast<char*>(lds) + off) = v;
    }
}
__device__ __forceinline__ bf16x8 frag_ld(const ushort* __restrict__ lds, int row, int colbyte) {
    int off = (row << 7) + (colbyte ^ ((row & 7) << 4));
    return *reinterpret_cast<const bf16x8*>(reinterpret_cast<const char*>(lds) + off);
}
// BK=32 variants (64 B rows)
__device__ __forceinline__ void stage_bf16_32(const ushort* __restrict__ src, int ld,
                                              ushort* __restrict__ lds, int t) {
#pragma unroll
    for (int it = 0; it < 2; ++it) {
        int e = (it * 256 + t) * 8;
        int row = e >> 5, col = e & 31;
        bf16x8 v = *reinterpret_cast<const bf16x8*>(src + (size_t)row * ld + col);
        int off = (row << 6) + ((col << 1) ^ ((row & 3) << 4));
        *reinterpret_cast<bf16x8*>(reinterpret_cast<char*>(lds) + off) = v;
    }
}
__device__ __forceinline__ bf16x8 frag32_ld(const ushort* __restrict__ lds, int row, int colbyte) {
    int off = (row << 6) + (colbyte ^ ((row & 3) << 4));
    return *reinterpret_cast<const bf16x8*>(reinterpret_cast<const char*>(lds) + off);
}

// ---------------- GEMM1: h1[br] = relu(x[br] (3840x2048 f32) @ W1[br] + b1[br]) -> bf16 3840x512
__global__ __launch_bounds__(256) void gemm1(const float* __restrict__ xs,
                                             const float* __restrict__ xo,
                                             const float* __restrict__ xu,
                                             const ushort* __restrict__ w1t,
                                             const float* __restrict__ b_s,
                                             const float* __restrict__ b_o,
                                             const float* __restrict__ b_u,
                                             ushort* __restrict__ h1out) {
    int br = blockIdx.z;
    const float* x = br == 0 ? xs : (br == 1 ? xo : xu);
    const ushort* wt = w1t + (size_t)br * 512 * 2048;
    const float* bias = br == 0 ? b_s : (br == 1 ? b_o : b_u);
    ushort* out = h1out + (size_t)br * 3840 * 512;

    __shared__ ushort As[128 * 64];
    __shared__ ushort Bs[128 * 64];
    int t = threadIdx.x, lane = t & 63, wid = t >> 6;
    int wr = wid >> 1, wc = wid & 1;
    int m0 = blockIdx.x * 128, n0 = blockIdx.y * 128;

    f32x4 acc[4][4] = {};
    for (int kt = 0; kt < 2048; kt += 64) {
        __syncthreads();
        stage_f32(x + (size_t)m0 * 2048 + kt, 2048, As, t);
        stage_bf16(wt + (size_t)n0 * 2048 + kt, 2048, Bs, t);
        __syncthreads();
#pragma unroll
        for (int kk = 0; kk < 64; kk += 32) {
            int cb = (kk + ((lane >> 4) << 3)) << 1;
            bf16x8 a[4], b[4];
#pragma unroll
            for (int f = 0; f < 4; f++) a[f] = frag_ld(As, wr * 64 + f * 16 + (lane & 15), cb);
#pragma unroll
            for (int f = 0; f < 4; f++) b[f] = frag_ld(Bs, wc * 64 + f * 16 + (lane & 15), cb);
#pragma unroll
            for (int i = 0; i < 4; i++)
#pragma unroll
                for (int j = 0; j < 4; j++)
                    acc[i][j] = __builtin_amdgcn_mfma_f32_16x16x32_bf16(a[i], b[j], acc[i][j], 0, 0, 0);
        }
    }
    int rb = m0 + wr * 64 + ((lane >> 4) << 2);
    int cb = n0 + wc * 64 + (lane & 15);
#pragma unroll
    for (int j = 0; j < 4; j++) {
        int col = cb + j * 16;
        float bv = bias[col];
#pragma unroll
        for (int i = 0; i < 4; i++) {
#pragma unroll
            for (int q = 0; q < 4; q++) {
                int row = rb + i * 16 + q;
                float v = acc[i][j][q] + bv;
                v = v > 0.f ? v : 0.f;
                out[(size_t)row * 512 + col] = f2bf(v);
            }
        }
    }
}

// ---------------- GEMM2 (3 branches in-block) + appear = relu(u)-relu(o)-relu(s) -> hin cols [0,256)
__global__ __launch_bounds__(256) void gemm2_appear(const ushort* __restrict__ h1,
                                                    const ushort* __restrict__ w2t,
                                                    const float* __restrict__ b_s,
                                                    const float* __restrict__ b_o,
                                                    const float* __restrict__ b_u,
                                                    ushort* __restrict__ hin) {
    __shared__ ushort As[128 * 64];
    __shared__ ushort Bs[128 * 64];
    int t = threadIdx.x, lane = t & 63, wid = t >> 6;
    int wr = wid >> 1, wc = wid & 1;
    int m0 = blockIdx.x * 128, n0 = blockIdx.y * 128;
    float res[4][4][4] = {};
    for (int br = 0; br < 3; ++br) {
        const ushort* A = h1 + (size_t)br * 3840 * 512;
        const ushort* B = w2t + (size_t)br * 256 * 512;
        const float* bias = br == 0 ? b_s : (br == 1 ? b_o : b_u);
        float sgn = (br == 2) ? 1.f : -1.f;
        f32x4 acc[4][4] = {};
        for (int kt = 0; kt < 512; kt += 64) {
            __syncthreads();
            stage_bf16(A + (size_t)m0 * 512 + kt, 512, As, t);
            stage_bf16(B + (size_t)n0 * 512 + kt, 512, Bs, t);
            __syncthreads();
#pragma unroll
            for (int kk = 0; kk < 64; kk += 32) {
                int cbyte = (kk + ((lane >> 4) << 3)) << 1;
                bf16x8 a[4], b[4];
#pragma unroll
                for (int f = 0; f < 4; f++) a[f] = frag_ld(As, wr * 64 + f * 16 + (lane & 15), cbyte);
#pragma unroll
                for (int f = 0; f < 4; f++) b[f] = frag_ld(Bs, wc * 64 + f * 16 + (lane & 15), cbyte);
#pragma unroll
                for (int i = 0; i < 4; i++)
#pragma unroll
                    for (int j = 0; j < 4; j++)
                        acc[i][j] = __builtin_amdgcn_mfma_f32_16x16x32_bf16(a[i], b[j], acc[i][j], 0, 0, 0);
            }
        }
#pragma unroll
        for (int j = 0; j < 4; j++) {
            float bv = bias[n0 + wc * 64 + j * 16 + (lane & 15)];
#pragma unroll
            for (int i = 0; i < 4; i++)
#pragma unroll
                for (int q = 0; q < 4; q++) {
                    float v = acc[i][j][q] + bv;
                    v = v > 0.f ? v : 0.f;
                    res[i][j][q] += sgn * v;
                }
        }
    }
    int rb = m0 + wr * 64 + ((lane >> 4) << 2);
    int cbse = n0 + wc * 64 + (lane & 15);
#pragma unroll
    for (int j = 0; j < 4; j++)
#pragma unroll
        for (int i = 0; i < 4; i++)
#pragma unroll
            for (int q = 0; q < 4; q++) {
                int row = rb + i * 16 + q, col = cbse + j * 16;
                hin[(size_t)row * 288 + col] = f2bf(res[i][j][q]);
            }
}

// ---------------- GEMM3: h2 = relu(hin (3840x288) @ Wc1pad + bc1) -> bf16 3840x256
__global__ __launch_bounds__(256) void gemm3(const ushort* __restrict__ hin,
                                             const ushort* __restrict__ wc1t,
                                             const float* __restrict__ bc1,
                                             ushort* __restrict__ h2) {
    __shared__ ushort As[128 * 32];
    __shared__ ushort Bs[128 * 32];
    int t = threadIdx.x, lane = t & 63, wid = t >> 6;
    int wr = wid >> 1, wc = wid & 1;
    int m0 = blockIdx.x * 128, n0 = blockIdx.y * 128;
    f32x4 acc[4][4] = {};
    for (int kt = 0; kt < 288; kt += 32) {
        __syncthreads();
        stage_bf16_32(hin + (size_t)m0 * 288 + kt, 288, As, t);
        stage_bf16_32(wc1t + (size_t)n0 * 288 + kt, 288, Bs, t);
        __syncthreads();
        int cbyte = ((lane >> 4) << 3) << 1;
        bf16x8 a[4], b[4];
#pragma unroll
        for (int f = 0; f < 4; f++) a[f] = frag32_ld(As, wr * 64 + f * 16 + (lane & 15), cbyte);
#pragma unroll
        for (int f = 0; f < 4; f++) b[f] = frag32_ld(Bs, wc * 64 + f * 16 + (lane & 15), cbyte);
#pragma unroll
        for (int i = 0; i < 4; i++)
#pragma unroll
            for (int j = 0; j < 4; j++)
                acc[i][j] = __builtin_amdgcn_mfma_f32_16x16x32_bf16(a[i], b[j], acc[i][j], 0, 0, 0);
    }
    int rb = m0 + wr * 64 + ((lane >> 4) << 2);
    int cbse = n0 + wc * 64 + (lane & 15);
#pragma unroll
    for (int j = 0; j < 4; j++) {
        int col = cbse + j * 16;
        float bv = bc1[col];
#pragma unroll
        for (int i = 0; i < 4; i++)
#pragma unroll
            for (int q = 0; q < 4; q++) {
                int row = rb + i * 16 + q;
                float v = acc[i][j][q] + bv;
                v = v > 0.f ? v : 0.f;
                h2[(size_t)row * 256 + col] = f2bf(v);
            }
    }
}

// ---------------- final: out = h2 (3840x256 bf16) @ Wc2 (256x3 f32) + bc2
__global__ void final_fc(const ushort* __restrict__ h2,
                         const float* __restrict__ wc2,
                         const float* __restrict__ bc2,
                         float* __restrict__ out) {
    __shared__ float w[768];
    int t = threadIdx.x;
    for (int i = t; i < 768; i += 256) w[i] = wc2[i];
    __syncthreads();
    int p = blockIdx.x * 256 + t;
    if (p >= N_PAIR) return;
    const ushort* hr = h2 + (size_t)p * 256;
    float s0 = bc2[0], s1 = bc2[1], s2 = bc2[2];
    for (int k = 0; k < 256; k++) {
        float h = bf2f(hr[k]);
        s0 += h * w[k * 3 + 0];
        s1 += h * w[k * 3 + 1];
        s2 += h * w[k * 3 + 2];
    }
    out[p * 3 + 0] = s0;
    out[p * 3 + 1] = s1;
    out[p * 3 + 2] = s2;
}

extern "C" void kernel_launch(void* const* d_in, const int* in_sizes, int n_in,
                              void* d_out, int out_size, void* d_ws, size_t ws_size,
                              hipStream_t stream) {
    (void)in_sizes; (void)n_in; (void)out_size; (void)ws_size;
    const float* xs = (const float*)d_in[0];
    const float* xo = (const float*)d_in[1];
    const float* xu = (const float*)d_in[2];
    const float* boxes = (const float*)d_in[3];
    const float* im_info = (const float*)d_in[4];
    const int* o1 = (const int*)d_in[5];
    const int* o2 = (const int*)d_in[6];
    const int* uu = (const int*)d_in[7];
    const int* im = (const int*)d_in[8];
    const float* Ws1 = (const float*)d_in[9];
    const float* bs1 = (const float*)d_in[10];
    const float* Ws2 = (const float*)d_in[11];
    const float* bs2 = (const float*)d_in[12];
    const float* Wo1 = (const float*)d_in[13];
    const float* bo1 = (const float*)d_in[14];
    const float* Wo2 = (const float*)d_in[15];
    const float* bo2 = (const float*)d_in[16];
    const float* Wu1 = (const float*)d_in[17];
    const float* bu1 = (const float*)d_in[18];
    const float* Wu2 = (const float*)d_in[19];
    const float* bu2 = (const float*)d_in[20];
    const float* Wc1 = (const float*)d_in[21];
    const float* bc1 = (const float*)d_in[22];
    const float* Wc2 = (const float*)d_in[23];
    const float* bc2 = (const float*)d_in[24];
    float* out = (float*)d_out;

    ushort* W1T = (ushort*)d_ws;                      // 3 * 512*2048
    ushort* W2T = W1T + (size_t)3 * 512 * 2048;       // 3 * 256*512
    ushort* WC1T = W2T + (size_t)3 * 256 * 512;       // 256*288
    ushort* H1 = WC1T + (size_t)256 * 288;            // 3 * 3840*512
    ushort* HIN = H1 + (size_t)3 * 3840 * 512;        // 3840*288
    ushort* H2 = HIN + (size_t)3840 * 288;            // 3840*256

    transpose_convert<<<dim3(32, 8, 3), 256, 0, stream>>>(Ws1, Wo1, Wu1, W1T, 2048, 512, 2048);
    transpose_convert<<<dim3(8, 4, 3), 256, 0, stream>>>(Ws2, Wo2, Wu2, W2T, 512, 256, 512);
    transpose_convert<<<dim3(5, 4, 1), 256, 0, stream>>>(Wc1, Wc1, Wc1, WC1T, 275, 256, 288);
    loc_kernel<<<15, 256, 0, stream>>>(boxes, im_info, o1, o2, uu, im, HIN);
    gemm1<<<dim3(30, 4, 3), 256, 0, stream>>>(xs, xo, xu, W1T, bs1, bo1, bu1, H1);
    gemm2_appear<<<dim3(30, 2), 256, 0, stream>>>(H1, W2T, bs2, bo2, bu2, HIN);
    gemm3<<<dim3(30, 2), 256, 0, stream>>>(HIN, WC1T, bc1, H2);
    final_fc<<<15, 256, 0, stream>>>(H2, Wc2, bc2, out);
}

// Round 2
// 105.009 us; speedup vs baseline: 1.5570x; 1.5570x over previous
//
#include <hip/hip_runtime.h>

#define N_PAIR 3840

typedef short bf16x8 __attribute__((ext_vector_type(8)));
typedef float f32x4 __attribute__((ext_vector_type(4)));

static __device__ __forceinline__ ushort f2bf(float f) {
    uint x = __float_as_uint(f);
    uint r = (x + 0x7FFFu + ((x >> 16) & 1u)) >> 16;
    return (ushort)r;
}
static __device__ __forceinline__ float bf2f(ushort u) {
    return __uint_as_float(((uint)u) << 16);
}

// ---------------- transpose + convert: in (K,N) f32 -> out (N,Kpad) bf16, zero-padded
__global__ void transpose_convert(const float* __restrict__ in0,
                                  const float* __restrict__ in1,
                                  const float* __restrict__ in2,
                                  ushort* __restrict__ out,
                                  int K, int N, int Kpad) {
    const float* in = (blockIdx.z == 0) ? in0 : (blockIdx.z == 1 ? in1 : in2);
    ushort* o = out + (size_t)blockIdx.z * N * Kpad;
    __shared__ float tile[64][65];
    int k0 = blockIdx.x * 64, n0 = blockIdx.y * 64;
    int t = threadIdx.x;
    int r = t >> 2, c4 = (t & 3) * 16;
#pragma unroll
    for (int i = 0; i < 16; i++) {
        int k = k0 + r, n = n0 + c4 + i;
        tile[r][c4 + i] = (k < K && n < N) ? in[(size_t)k * N + n] : 0.f;
    }
    __syncthreads();
#pragma unroll
    for (int i = 0; i < 16; i++) {
        int n = n0 + r, k = k0 + c4 + i;
        if (n < N && k < Kpad) o[(size_t)n * Kpad + k] = f2bf(tile[c4 + i][r]);
    }
}

// W2 (z=0..2) + Wc1 (z=3) in one launch
__global__ void transpose_convert2(const float* __restrict__ Ws2,
                                   const float* __restrict__ Wo2,
                                   const float* __restrict__ Wu2,
                                   const float* __restrict__ Wc1,
                                   ushort* __restrict__ W2T,
                                   ushort* __restrict__ WC1T) {
    int z = blockIdx.z;
    const float* in; ushort* o; int K, N, Kpad;
    if (z < 3) {
        in = (z == 0) ? Ws2 : (z == 1 ? Wo2 : Wu2);
        o = W2T + (size_t)z * 256 * 512; K = 512; N = 256; Kpad = 512;
    } else {
        in = Wc1; o = WC1T; K = 275; N = 256; Kpad = 288;
    }
    __shared__ float tile[64][65];
    int k0 = blockIdx.x * 64, n0 = blockIdx.y * 64;
    int t = threadIdx.x;
    int r = t >> 2, c4 = (t & 3) * 16;
#pragma unroll
    for (int i = 0; i < 16; i++) {
        int k = k0 + r, n = n0 + c4 + i;
        tile[r][c4 + i] = (k < K && n < N) ? in[(size_t)k * N + n] : 0.f;
    }
    __syncthreads();
#pragma unroll
    for (int i = 0; i < 16; i++) {
        int n = n0 + r, k = k0 + c4 + i;
        if (n < N && k < Kpad) o[(size_t)n * Kpad + k] = f2bf(tile[c4 + i][r]);
    }
}

// ---------------- LDS helpers: 128B rows (BK=64), XOR swizzle
__device__ __forceinline__ bf16x8 frag_ld(const ushort* __restrict__ lds, int row, int colbyte) {
    int off = (row << 7) + (colbyte ^ ((row & 7) << 4));
    return *reinterpret_cast<const bf16x8*>(reinterpret_cast<const char*>(lds) + off);
}
// 64B rows (BK=32)
__device__ __forceinline__ bf16x8 frag32_ld(const ushort* __restrict__ lds, int row, int colbyte) {
    int off = (row << 6) + (colbyte ^ ((row & 3) << 4));
    return *reinterpret_cast<const bf16x8*>(reinterpret_cast<const char*>(lds) + off);
}

// ---------------- GEMM1: h1[br] = relu(x (3840x2048 f32) @ W1t + b1) -> bf16 3840x512
// BM=64 BN=128 BK=64, 4 waves (2x2), single-barrier dbuf pipeline, reg prefetch
__global__ __launch_bounds__(256) void gemm1(const float* __restrict__ xs,
                                             const float* __restrict__ xo,
                                             const float* __restrict__ xu,
                                             const ushort* __restrict__ w1t,
                                             const float* __restrict__ b_s,
                                             const float* __restrict__ b_o,
                                             const float* __restrict__ b_u,
                                             ushort* __restrict__ h1out) {
    int br = blockIdx.z;
    const float* x = br == 0 ? xs : (br == 1 ? xo : xu);
    const ushort* wt = w1t + (size_t)br * 512 * 2048;
    const float* bias = br == 0 ? b_s : (br == 1 ? b_o : b_u);
    ushort* out = h1out + (size_t)br * 3840 * 512;

    __shared__ ushort As[2][64 * 64];
    __shared__ ushort Bs[2][128 * 64];
    int t = threadIdx.x, lane = t & 63, wid = t >> 6;
    int wr = wid >> 1, wc = wid & 1;
    int m0 = blockIdx.x * 64, n0 = blockIdx.y * 128;
    const float* asrc = x + (size_t)m0 * 2048;
    const ushort* bsrc = wt + (size_t)n0 * 2048;

    // A: thread loads 16 f32 at (ar, ac..ac+15); B: 4x bf16x8
    int ar = t >> 2, ac = (t & 3) * 16;
    float4 pa[4];
    bf16x8 pb[4];

    auto issue = [&](int kt) {
        const float4* g = reinterpret_cast<const float4*>(asrc + (size_t)ar * 2048 + kt + ac);
#pragma unroll
        for (int i = 0; i < 4; i++) pa[i] = g[i];
#pragma unroll
        for (int it = 0; it < 4; it++) {
            int e = (it * 256 + t) * 8;
            int rr = e >> 6, cc = e & 63;
            pb[it] = *reinterpret_cast<const bf16x8*>(bsrc + (size_t)rr * 2048 + kt + cc);
        }
    };
    auto commit = [&](int buf) {
        union { bf16x8 v; ushort us[8]; } p0, p1;
#pragma unroll
        for (int i = 0; i < 4; i++) {
            p0.us[i] = f2bf(pa[0][i]); p0.us[4 + i] = f2bf(pa[1][i]);
            p1.us[i] = f2bf(pa[2][i]); p1.us[4 + i] = f2bf(pa[3][i]);
        }
        char* ab = reinterpret_cast<char*>(&As[buf][0]);
        int off0 = (ar << 7) + (((ac) << 1) ^ ((ar & 7) << 4));
        int off1 = (ar << 7) + (((ac + 8) << 1) ^ ((ar & 7) << 4));
        *reinterpret_cast<bf16x8*>(ab + off0) = p0.v;
        *reinterpret_cast<bf16x8*>(ab + off1) = p1.v;
        char* bb = reinterpret_cast<char*>(&Bs[buf][0]);
#pragma unroll
        for (int it = 0; it < 4; it++) {
            int e = (it * 256 + t) * 8;
            int rr = e >> 6, cc = e & 63;
            int off = (rr << 7) + ((cc << 1) ^ ((rr & 7) << 4));
            *reinterpret_cast<bf16x8*>(bb + off) = pb[it];
        }
    };

    f32x4 acc[2][4] = {};
    issue(0);
    commit(0);
    __syncthreads();
    int cur = 0;
    for (int kt = 0; kt < 2048; kt += 64) {
        int nxt = kt + 64;
        if (nxt < 2048) issue(nxt);
#pragma unroll
        for (int kk = 0; kk < 64; kk += 32) {
            int cb = (kk + ((lane >> 4) << 3)) << 1;
            bf16x8 a[2], b[4];
#pragma unroll
            for (int i = 0; i < 2; i++) a[i] = frag_ld(&As[cur][0], wr * 32 + i * 16 + (lane & 15), cb);
#pragma unroll
            for (int f = 0; f < 4; f++) b[f] = frag_ld(&Bs[cur][0], wc * 64 + f * 16 + (lane & 15), cb);
#pragma unroll
            for (int i = 0; i < 2; i++)
#pragma unroll
                for (int j = 0; j < 4; j++)
                    acc[i][j] = __builtin_amdgcn_mfma_f32_16x16x32_bf16(a[i], b[j], acc[i][j], 0, 0, 0);
        }
        if (nxt < 2048) commit(cur ^ 1);
        __syncthreads();
        cur ^= 1;
    }
    int rb = m0 + wr * 32 + ((lane >> 4) << 2);
    int cb0 = n0 + wc * 64 + (lane & 15);
#pragma unroll
    for (int j = 0; j < 4; j++) {
        int col = cb0 + j * 16;
        float bv = bias[col];
#pragma unroll
        for (int i = 0; i < 2; i++)
#pragma unroll
            for (int q = 0; q < 4; q++) {
                int row = rb + i * 16 + q;
                float v = acc[i][j][q] + bv;
                v = v > 0.f ? v : 0.f;
                out[(size_t)row * 512 + col] = f2bf(v);
            }
    }
}

// ---------------- GEMM2 batched over branches: h2br = relu(h1 @ W2t + b2) -> bf16 3x3840x256
__global__ __launch_bounds__(256) void gemm2(const ushort* __restrict__ h1,
                                             const ushort* __restrict__ w2t,
                                             const float* __restrict__ b_s,
                                             const float* __restrict__ b_o,
                                             const float* __restrict__ b_u,
                                             ushort* __restrict__ h2br) {
    int br = blockIdx.z;
    const ushort* A = h1 + (size_t)br * 3840 * 512;
    const ushort* B = w2t + (size_t)br * 256 * 512;
    const float* bias = br == 0 ? b_s : (br == 1 ? b_o : b_u);
    ushort* out = h2br + (size_t)br * 3840 * 256;

    __shared__ ushort As[2][64 * 64];
    __shared__ ushort Bs[2][128 * 64];
    int t = threadIdx.x, lane = t & 63, wid = t >> 6;
    int wr = wid >> 1, wc = wid & 1;
    int m0 = blockIdx.x * 64, n0 = blockIdx.y * 128;
    const ushort* asrc = A + (size_t)m0 * 512;
    const ushort* bsrc = B + (size_t)n0 * 512;

    int ar = t >> 2, ac = (t & 3) * 16;
    bf16x8 pa[2], pb[4];
    auto issue = [&](int kt) {
        const bf16x8* g = reinterpret_cast<const bf16x8*>(asrc + (size_t)ar * 512 + kt + ac);
        pa[0] = g[0]; pa[1] = g[1];
#pragma unroll
        for (int it = 0; it < 4; it++) {
            int e = (it * 256 + t) * 8;
            int rr = e >> 6, cc = e & 63;
            pb[it] = *reinterpret_cast<const bf16x8*>(bsrc + (size_t)rr * 512 + kt + cc);
        }
    };
    auto commit = [&](int buf) {
        char* ab = reinterpret_cast<char*>(&As[buf][0]);
        int off0 = (ar << 7) + ((ac << 1) ^ ((ar & 7) << 4));
        int off1 = (ar << 7) + (((ac + 8) << 1) ^ ((ar & 7) << 4));
        *reinterpret_cast<bf16x8*>(ab + off0) = pa[0];
        *reinterpret_cast<bf16x8*>(ab + off1) = pa[1];
        char* bb = reinterpret_cast<char*>(&Bs[buf][0]);
#pragma unroll
        for (int it = 0; it < 4; it++) {
            int e = (it * 256 + t) * 8;
            int rr = e >> 6, cc = e & 63;
            int off = (rr << 7) + ((cc << 1) ^ ((rr & 7) << 4));
            *reinterpret_cast<bf16x8*>(bb + off) = pb[it];
        }
    };

    f32x4 acc[2][4] = {};
    issue(0);
    commit(0);
    __syncthreads();
    int cur = 0;
    for (int kt = 0; kt < 512; kt += 64) {
        int nxt = kt + 64;
        if (nxt < 512) issue(nxt);
#pragma unroll
        for (int kk = 0; kk < 64; kk += 32) {
            int cb = (kk + ((lane >> 4) << 3)) << 1;
            bf16x8 a[2], b[4];
#pragma unroll
            for (int i = 0; i < 2; i++) a[i] = frag_ld(&As[cur][0], wr * 32 + i * 16 + (lane & 15), cb);
#pragma unroll
            for (int f = 0; f < 4; f++) b[f] = frag_ld(&Bs[cur][0], wc * 64 + f * 16 + (lane & 15), cb);
#pragma unroll
            for (int i = 0; i < 2; i++)
#pragma unroll
                for (int j = 0; j < 4; j++)
                    acc[i][j] = __builtin_amdgcn_mfma_f32_16x16x32_bf16(a[i], b[j], acc[i][j], 0, 0, 0);
        }
        if (nxt < 512) commit(cur ^ 1);
        __syncthreads();
        cur ^= 1;
    }
    int rb = m0 + wr * 32 + ((lane >> 4) << 2);
    int cb0 = n0 + wc * 64 + (lane & 15);
#pragma unroll
    for (int j = 0; j < 4; j++) {
        int col = cb0 + j * 16;
        float bv = bias[col];
#pragma unroll
        for (int i = 0; i < 2; i++)
#pragma unroll
            for (int q = 0; q < 4; q++) {
                int row = rb + i * 16 + q;
                float v = acc[i][j][q] + bv;
                v = v > 0.f ? v : 0.f;
                out[(size_t)row * 256 + col] = f2bf(v);
            }
    }
}

// ---------------- appear = u - o - s -> hin[:,0:256); loc features -> hin[:,256:288)
__global__ void appear_pack(const ushort* __restrict__ h2br,
                            ushort* __restrict__ hin,
                            const float* __restrict__ boxes,
                            const float* __restrict__ im_info,
                            const int* __restrict__ o1, const int* __restrict__ o2,
                            const int* __restrict__ u, const int* __restrict__ im) {
    int i = blockIdx.x * 256 + threadIdx.x; // chunk over 3840*256/8
    if (i < N_PAIR * 32) {
        int p = i >> 5, ch = (i & 31) * 8;
        const ushort* ps = h2br + (size_t)p * 256 + ch;
        bf16x8 vs = *reinterpret_cast<const bf16x8*>(ps);
        bf16x8 vo = *reinterpret_cast<const bf16x8*>(ps + (size_t)3840 * 256);
        bf16x8 vu = *reinterpret_cast<const bf16x8*>(ps + (size_t)2 * 3840 * 256);
        union { bf16x8 v; ushort us[8]; } r;
#pragma unroll
        for (int j = 0; j < 8; j++)
            r.us[j] = f2bf(bf2f(((ushort)vu[j])) - bf2f(((ushort)vo[j])) - bf2f(((ushort)vs[j])));
        *reinterpret_cast<bf16x8*>(hin + (size_t)p * 288 + ch) = r.v;
    }
    if (blockIdx.x < 15) {
        int p = blockIdx.x * 256 + threadIdx.x;
        const float* sb = boxes + 5 * o1[p] + 1;
        const float* ob = boxes + 5 * o2[p] + 1;
        const float* ub = boxes + 5 * u[p] + 1;
        const float* ii = im_info + 3 * im[p];
        float hi = ii[0], wi = ii[1];
        float x_s = (sb[0] + sb[2]) * 0.5f, y_s = (sb[1] + sb[3]) * 0.5f;
        float w_s = sb[2] - sb[0], h_s = sb[3] - sb[1];
        float x_o = (ob[0] + ob[2]) * 0.5f, y_o = (ob[1] + ob[3]) * 0.5f;
        float w_o = ob[2] - ob[0], h_o = ob[3] - ob[1];
        float a_s = w_s * h_s, a_o = w_o * h_o;
        float a_u = (ub[2] - ub[0]) * (ub[3] - ub[1]);
        float area = wi * hi;
        float f[19];
        f[0] = x_s / wi;            f[1] = y_s / hi;
        f[2] = (x_s + w_s) / wi;    f[3] = (y_s + h_s) / hi;
        f[4] = a_s / area;
        f[5] = x_o / wi;            f[6] = y_o / hi;
        f[7] = (x_o + w_o) / wi;    f[8] = (y_o + h_o) / hi;
        f[9] = a_o / area;
        f[10] = (x_s - x_o) / w_o;  f[11] = (y_s - y_o) / h_o;
        f[12] = logf(w_s / w_o);    f[13] = logf(h_s / h_o);
        f[14] = (x_o - x_s) / w_s;  f[15] = (y_o - y_s) / h_s;
        f[16] = logf(w_o / w_s);    f[17] = logf(h_o / h_s);
        f[18] = a_u / area;
        ushort* row = hin + (size_t)p * 288 + 256;
#pragma unroll
        for (int k = 0; k < 19; k++) row[k] = f2bf(f[k]);
#pragma unroll
        for (int k = 19; k < 32; k++) row[k] = 0;
    }
}

// ---------------- GEMM3: h2 = relu(hin (3840x288) @ Wc1t + bc1) -> bf16 3840x256
// BM=64 BN=128 BK=32, pipelined
__global__ __launch_bounds__(256) void gemm3(const ushort* __restrict__ hin,
                                             const ushort* __restrict__ wc1t,
                                             const float* __restrict__ bc1,
                                             ushort* __restrict__ h2) {
    __shared__ ushort As[2][64 * 32];
    __shared__ ushort Bs[2][128 * 32];
    int t = threadIdx.x, lane = t & 63, wid = t >> 6;
    int wr = wid >> 1, wc = wid & 1;
    int m0 = blockIdx.x * 64, n0 = blockIdx.y * 128;
    const ushort* asrc = hin + (size_t)m0 * 288;
    const ushort* bsrc = wc1t + (size_t)n0 * 288;

    int ar = t >> 2, ac = (t & 3) * 8;
    bf16x8 pa, pb[2];
    auto issue = [&](int kt) {
        pa = *reinterpret_cast<const bf16x8*>(asrc + (size_t)ar * 288 + kt + ac);
#pragma unroll
        for (int it = 0; it < 2; it++) {
            int e = (it * 256 + t) * 8;
            int rr = e >> 5, cc = e & 31;
            pb[it] = *reinterpret_cast<const bf16x8*>(bsrc + (size_t)rr * 288 + kt + cc);
        }
    };
    auto commit = [&](int buf) {
        char* ab = reinterpret_cast<char*>(&As[buf][0]);
        int off0 = (ar << 6) + ((ac << 1) ^ ((ar & 3) << 4));
        *reinterpret_cast<bf16x8*>(ab + off0) = pa;
        char* bb = reinterpret_cast<char*>(&Bs[buf][0]);
#pragma unroll
        for (int it = 0; it < 2; it++) {
            int e = (it * 256 + t) * 8;
            int rr = e >> 5, cc = e & 31;
            int off = (rr << 6) + ((cc << 1) ^ ((rr & 3) << 4));
            *reinterpret_cast<bf16x8*>(bb + off) = pb[it];
        }
    };

    f32x4 acc[2][4] = {};
    issue(0);
    commit(0);
    __syncthreads();
    int cur = 0;
    for (int kt = 0; kt < 288; kt += 32) {
        int nxt = kt + 32;
        if (nxt < 288) issue(nxt);
        int cb = ((lane >> 4) << 3) << 1;
        bf16x8 a[2], b[4];
#pragma unroll
        for (int i = 0; i < 2; i++) a[i] = frag32_ld(&As[cur][0], wr * 32 + i * 16 + (lane & 15), cb);
#pragma unroll
        for (int f = 0; f < 4; f++) b[f] = frag32_ld(&Bs[cur][0], wc * 64 + f * 16 + (lane & 15), cb);
#pragma unroll
        for (int i = 0; i < 2; i++)
#pragma unroll
            for (int j = 0; j < 4; j++)
                acc[i][j] = __builtin_amdgcn_mfma_f32_16x16x32_bf16(a[i], b[j], acc[i][j], 0, 0, 0);
        if (nxt < 288) commit(cur ^ 1);
        __syncthreads();
        cur ^= 1;
    }
    int rb = m0 + wr * 32 + ((lane >> 4) << 2);
    int cb0 = n0 + wc * 64 + (lane & 15);
#pragma unroll
    for (int j = 0; j < 4; j++) {
        int col = cb0 + j * 16;
        float bv = bc1[col];
#pragma unroll
        for (int i = 0; i < 2; i++)
#pragma unroll
            for (int q = 0; q < 4; q++) {
                int row = rb + i * 16 + q;
                float v = acc[i][j][q] + bv;
                v = v > 0.f ? v : 0.f;
                h2[(size_t)row * 256 + col] = f2bf(v);
            }
    }
}

// ---------------- final: out = h2 (3840x256 bf16) @ Wc2 (256x3 f32) + bc2
// 16 threads per row, shuffle reduce
__global__ void final_fc(const ushort* __restrict__ h2,
                         const float* __restrict__ wc2,
                         const float* __restrict__ bc2,
                         float* __restrict__ out) {
    __shared__ float w[768];
    int t = threadIdx.x;
    for (int i = t; i < 768; i += 256) w[i] = wc2[i];
    __syncthreads();
    int g = t >> 4, l = t & 15;
    int row = blockIdx.x * 16 + g;
    const ushort* hr = h2 + (size_t)row * 256 + l * 16;
    bf16x8 v0 = *reinterpret_cast<const bf16x8*>(hr);
    bf16x8 v1 = *reinterpret_cast<const bf16x8*>(hr + 8);
    float s0 = 0.f, s1 = 0.f, s2 = 0.f;
#pragma unroll
    for (int k = 0; k < 8; k++) {
        float h = bf2f((ushort)v0[k]);
        int c = (l * 16 + k) * 3;
        s0 += h * w[c]; s1 += h * w[c + 1]; s2 += h * w[c + 2];
    }
#pragma unroll
    for (int k = 0; k < 8; k++) {
        float h = bf2f((ushort)v1[k]);
        int c = (l * 16 + 8 + k) * 3;
        s0 += h * w[c]; s1 += h * w[c + 1]; s2 += h * w[c + 2];
    }
#pragma unroll
    for (int m = 1; m < 16; m <<= 1) {
        s0 += __shfl_xor(s0, m);
        s1 += __shfl_xor(s1, m);
        s2 += __shfl_xor(s2, m);
    }
    if (l == 0) {
        out[row * 3 + 0] = s0 + bc2[0];
        out[row * 3 + 1] = s1 + bc2[1];
        out[row * 3 + 2] = s2 + bc2[2];
    }
}

extern "C" void kernel_launch(void* const* d_in, const int* in_sizes, int n_in,
                              void* d_out, int out_size, void* d_ws, size_t ws_size,
                              hipStream_t stream) {
    (void)in_sizes; (void)n_in; (void)out_size; (void)ws_size;
    const float* xs = (const float*)d_in[0];
    const float* xo = (const float*)d_in[1];
    const float* xu = (const float*)d_in[2];
    const float* boxes = (const float*)d_in[3];
    const float* im_info = (const float*)d_in[4];
    const int* o1 = (const int*)d_in[5];
    const int* o2 = (const int*)d_in[6];
    const int* uu = (const int*)d_in[7];
    const int* im = (const int*)d_in[8];
    const float* Ws1 = (const float*)d_in[9];
    const float* bs1 = (const float*)d_in[10];
    const float* Ws2 = (const float*)d_in[11];
    const float* bs2 = (const float*)d_in[12];
    const float* Wo1 = (const float*)d_in[13];
    const float* bo1 = (const float*)d_in[14];
    const float* Wo2 = (const float*)d_in[15];
    const float* bo2 = (const float*)d_in[16];
    const float* Wu1 = (const float*)d_in[17];
    const float* bu1 = (const float*)d_in[18];
    const float* Wu2 = (const float*)d_in[19];
    const float* bu2 = (const float*)d_in[20];
    const float* Wc1 = (const float*)d_in[21];
    const float* bc1 = (const float*)d_in[22];
    const float* Wc2 = (const float*)d_in[23];
    const float* bc2 = (const float*)d_in[24];
    float* out = (float*)d_out;

    ushort* W1T = (ushort*)d_ws;                      // 3 * 512*2048 = 3,145,728
    ushort* H2BR = W1T;                               // alias: 3 * 3840*256 = 2,949,120 (<= W1T size; used after gemm1)
    ushort* W2T = W1T + (size_t)3 * 512 * 2048;       // 3 * 256*512
    ushort* WC1T = W2T + (size_t)3 * 256 * 512;       // 256*288
    ushort* H1 = WC1T + (size_t)256 * 288;            // 3 * 3840*512
    ushort* HIN = H1 + (size_t)3 * 3840 * 512;        // 3840*288
    ushort* H2 = HIN + (size_t)3840 * 288;            // 3840*256

    transpose_convert<<<dim3(32, 8, 3), 256, 0, stream>>>(Ws1, Wo1, Wu1, W1T, 2048, 512, 2048);
    transpose_convert2<<<dim3(8, 4, 4), 256, 0, stream>>>(Ws2, Wo2, Wu2, Wc1, W2T, WC1T);
    gemm1<<<dim3(60, 4, 3), 256, 0, stream>>>(xs, xo, xu, W1T, bs1, bo1, bu1, H1);
    gemm2<<<dim3(60, 2, 3), 256, 0, stream>>>(H1, W2T, bs2, bo2, bu2, H2BR);
    appear_pack<<<480, 256, 0, stream>>>(H2BR, HIN, boxes, im_info, o1, o2, uu, im);
    gemm3<<<dim3(60, 2), 256, 0, stream>>>(HIN, WC1T, bc1, H2);
    final_fc<<<240, 256, 0, stream>>>(H2, Wc2, bc2, out);
}

// Round 3
// 97.220 us; speedup vs baseline: 1.6818x; 1.0801x over previous
//
#include <hip/hip_runtime.h>

#define N_PAIR 3840

typedef short bf16x8 __attribute__((ext_vector_type(8)));
typedef float f32x4 __attribute__((ext_vector_type(4)));

static __device__ __forceinline__ ushort f2bf(float f) {
    uint x = __float_as_uint(f);
    uint r = (x + 0x7FFFu + ((x >> 16) & 1u)) >> 16;
    return (ushort)r;
}
static __device__ __forceinline__ float bf2f(ushort u) {
    return __uint_as_float(((uint)u) << 16);
}

// ---------------- transpose + convert: in (K,N) f32 -> out (N,Kpad) bf16, zero-padded
__global__ void transpose_convert(const float* __restrict__ in0,
                                  const float* __restrict__ in1,
                                  const float* __restrict__ in2,
                                  ushort* __restrict__ out,
                                  int K, int N, int Kpad) {
    const float* in = (blockIdx.z == 0) ? in0 : (blockIdx.z == 1 ? in1 : in2);
    ushort* o = out + (size_t)blockIdx.z * N * Kpad;
    __shared__ float tile[64][65];
    int k0 = blockIdx.x * 64, n0 = blockIdx.y * 64;
    int t = threadIdx.x;
    int r = t >> 2, c4 = (t & 3) * 16;
#pragma unroll
    for (int i = 0; i < 16; i++) {
        int k = k0 + r, n = n0 + c4 + i;
        tile[r][c4 + i] = (k < K && n < N) ? in[(size_t)k * N + n] : 0.f;
    }
    __syncthreads();
#pragma unroll
    for (int i = 0; i < 16; i++) {
        int n = n0 + r, k = k0 + c4 + i;
        if (n < N && k < Kpad) o[(size_t)n * Kpad + k] = f2bf(tile[c4 + i][r]);
    }
}

// W2 (z=0..2) + Wc1 (z=3) in one launch
__global__ void transpose_convert2(const float* __restrict__ Ws2,
                                   const float* __restrict__ Wo2,
                                   const float* __restrict__ Wu2,
                                   const float* __restrict__ Wc1,
                                   ushort* __restrict__ W2T,
                                   ushort* __restrict__ WC1T) {
    int z = blockIdx.z;
    const float* in; ushort* o; int K, N, Kpad;
    if (z < 3) {
        in = (z == 0) ? Ws2 : (z == 1 ? Wo2 : Wu2);
        o = W2T + (size_t)z * 256 * 512; K = 512; N = 256; Kpad = 512;
    } else {
        in = Wc1; o = WC1T; K = 275; N = 256; Kpad = 288;
    }
    __shared__ float tile[64][65];
    int k0 = blockIdx.x * 64, n0 = blockIdx.y * 64;
    int t = threadIdx.x;
    int r = t >> 2, c4 = (t & 3) * 16;
#pragma unroll
    for (int i = 0; i < 16; i++) {
        int k = k0 + r, n = n0 + c4 + i;
        tile[r][c4 + i] = (k < K && n < N) ? in[(size_t)k * N + n] : 0.f;
    }
    __syncthreads();
#pragma unroll
    for (int i = 0; i < 16; i++) {
        int n = n0 + r, k = k0 + c4 + i;
        if (n < N && k < Kpad) o[(size_t)n * Kpad + k] = f2bf(tile[c4 + i][r]);
    }
}

// ---------------- LDS helpers: 128B rows (BK=64), XOR swizzle
__device__ __forceinline__ bf16x8 frag_ld(const ushort* __restrict__ lds, int row, int colbyte) {
    int off = (row << 7) + (colbyte ^ ((row & 7) << 4));
    return *reinterpret_cast<const bf16x8*>(reinterpret_cast<const char*>(lds) + off);
}
// 64B rows (BK=32)
__device__ __forceinline__ bf16x8 frag32_ld(const ushort* __restrict__ lds, int row, int colbyte) {
    int off = (row << 6) + (colbyte ^ ((row & 3) << 4));
    return *reinterpret_cast<const bf16x8*>(reinterpret_cast<const char*>(lds) + off);
}

// ---------------- GEMM1: h1[br] = relu(x (3840x2048 f32) @ W1t + b1) -> bf16 3840x512
// BM=64 BN=128 BK=64, 4 waves (2x2), 2-deep register prefetch, XCD-chunked swizzle
__global__ __launch_bounds__(256) void gemm1(const float* __restrict__ xs,
                                             const float* __restrict__ xo,
                                             const float* __restrict__ xu,
                                             const ushort* __restrict__ w1t,
                                             const float* __restrict__ b_s,
                                             const float* __restrict__ b_o,
                                             const float* __restrict__ b_u,
                                             ushort* __restrict__ h1out) {
    // 720 blocks = 8 XCDs x 90: chunked swizzle, y fastest (A-sharing blocks adjacent)
    int bid = blockIdx.x;
    int w = (bid & 7) * 90 + (bid >> 3);
    int br = w / 240; int r = w - br * 240;
    int xt = r >> 2, yt = r & 3;

    const float* x = br == 0 ? xs : (br == 1 ? xo : xu);
    const ushort* wt = w1t + (size_t)br * 512 * 2048;
    const float* bias = br == 0 ? b_s : (br == 1 ? b_o : b_u);
    ushort* out = h1out + (size_t)br * 3840 * 512;

    __shared__ ushort As[2][64 * 64];
    __shared__ ushort Bs[2][128 * 64];
    int t = threadIdx.x, lane = t & 63, wid = t >> 6;
    int wr = wid >> 1, wc = wid & 1;
    int m0 = xt * 64, n0 = yt * 128;
    const float* asrc = x + (size_t)m0 * 2048;
    const ushort* bsrc = wt + (size_t)n0 * 2048;

    int ar = t >> 2, ac = (t & 3) * 16;

    // two named prefetch sets (no runtime-indexed vector arrays -> stay in regs)
    float4 pa0[4], pa1[4];
    bf16x8 pb0[4], pb1[4];

#define G1_ISSUE(PA, PB, KT)                                                              \
    {                                                                                     \
        const float4* g = reinterpret_cast<const float4*>(asrc + (size_t)ar * 2048 + (KT) + ac); \
        PA[0] = g[0]; PA[1] = g[1]; PA[2] = g[2]; PA[3] = g[3];                           \
        _Pragma("unroll")                                                                 \
        for (int it = 0; it < 4; it++) {                                                  \
            int e = (it * 256 + t) * 8;                                                   \
            int rr = e >> 6, cc = e & 63;                                                 \
            PB[it] = *reinterpret_cast<const bf16x8*>(bsrc + (size_t)rr * 2048 + (KT) + cc); \
        }                                                                                 \
    }
#define G1_COMMIT(PA, PB, BUF)                                                            \
    {                                                                                     \
        union { bf16x8 v; ushort us[8]; } p0, p1;                                         \
        _Pragma("unroll")                                                                 \
        for (int i = 0; i < 4; i++) {                                                     \
            p0.us[i] = f2bf(PA[0][i]); p0.us[4 + i] = f2bf(PA[1][i]);                     \
            p1.us[i] = f2bf(PA[2][i]); p1.us[4 + i] = f2bf(PA[3][i]);                     \
        }                                                                                 \
        char* ab = reinterpret_cast<char*>(&As[BUF][0]);                                  \
        int off0 = (ar << 7) + ((ac << 1) ^ ((ar & 7) << 4));                             \
        int off1 = (ar << 7) + (((ac + 8) << 1) ^ ((ar & 7) << 4));                       \
        *reinterpret_cast<bf16x8*>(ab + off0) = p0.v;                                     \
        *reinterpret_cast<bf16x8*>(ab + off1) = p1.v;                                     \
        char* bb = reinterpret_cast<char*>(&Bs[BUF][0]);                                  \
        _Pragma("unroll")                                                                 \
        for (int it = 0; it < 4; it++) {                                                  \
            int e = (it * 256 + t) * 8;                                                   \
            int rr = e >> 6, cc = e & 63;                                                 \
            int off = (rr << 7) + ((cc << 1) ^ ((rr & 7) << 4));                          \
            *reinterpret_cast<bf16x8*>(bb + off) = PB[it];                                \
        }                                                                                 \
    }
#define G1_MFMA(BUF)                                                                      \
    _Pragma("unroll")                                                                     \
    for (int kk = 0; kk < 64; kk += 32) {                                                 \
        int cb = (kk + ((lane >> 4) << 3)) << 1;                                          \
        bf16x8 a[2], b[4];                                                                \
        _Pragma("unroll")                                                                 \
        for (int i = 0; i < 2; i++) a[i] = frag_ld(&As[BUF][0], wr * 32 + i * 16 + (lane & 15), cb); \
        _Pragma("unroll")                                                                 \
        for (int f = 0; f < 4; f++) b[f] = frag_ld(&Bs[BUF][0], wc * 64 + f * 16 + (lane & 15), cb); \
        _Pragma("unroll")                                                                 \
        for (int i = 0; i < 2; i++)                                                       \
            _Pragma("unroll")                                                             \
            for (int j = 0; j < 4; j++)                                                   \
                acc[i][j] = __builtin_amdgcn_mfma_f32_16x16x32_bf16(a[i], b[j], acc[i][j], 0, 0, 0); \
    }

    f32x4 acc[2][4] = {};
    // prologue: t0 -> set1 -> buf0; t1 -> set0 (pending)
    G1_ISSUE(pa1, pb1, 0)
    G1_COMMIT(pa1, pb1, 0)
    G1_ISSUE(pa0, pb0, 64)
    __syncthreads();
    // invariant: at even t, set0 holds t+1; at odd t, set1 holds t+1
    for (int kt = 0; kt < 2048; kt += 128) {
        // even iter: read buf0, commit set0 -> buf1, issue t+2 -> set1
        if (kt + 128 < 2048) G1_ISSUE(pa1, pb1, kt + 128)
        G1_MFMA(0)
        if (kt + 64 < 2048) G1_COMMIT(pa0, pb0, 1)
        __syncthreads();
        // odd iter: read buf1, commit set1 -> buf0, issue t+3 -> set0
        if (kt + 192 < 2048) G1_ISSUE(pa0, pb0, kt + 192)
        G1_MFMA(1)
        if (kt + 128 < 2048) G1_COMMIT(pa1, pb1, 0)
        __syncthreads();
    }
    int rb = m0 + wr * 32 + ((lane >> 4) << 2);
    int cb0 = n0 + wc * 64 + (lane & 15);
#pragma unroll
    for (int j = 0; j < 4; j++) {
        int col = cb0 + j * 16;
        float bv = bias[col];
#pragma unroll
        for (int i = 0; i < 2; i++)
#pragma unroll
            for (int q = 0; q < 4; q++) {
                int row = rb + i * 16 + q;
                float v = acc[i][j][q] + bv;
                v = v > 0.f ? v : 0.f;
                out[(size_t)row * 512 + col] = f2bf(v);
            }
    }
#undef G1_ISSUE
#undef G1_COMMIT
#undef G1_MFMA
}

// ---------------- GEMM2 batched over branches: h2br = relu(h1 @ W2t + b2) -> bf16 3x3840x256
__global__ __launch_bounds__(256) void gemm2(const ushort* __restrict__ h1,
                                             const ushort* __restrict__ w2t,
                                             const float* __restrict__ b_s,
                                             const float* __restrict__ b_o,
                                             const float* __restrict__ b_u,
                                             ushort* __restrict__ h2br) {
    // 360 blocks = 8 x 45, y fastest
    int bid = blockIdx.x;
    int w = (bid & 7) * 45 + (bid >> 3);
    int br = w / 120; int r = w - br * 120;
    int xt = r >> 1, yt = r & 1;

    const ushort* A = h1 + (size_t)br * 3840 * 512;
    const ushort* B = w2t + (size_t)br * 256 * 512;
    const float* bias = br == 0 ? b_s : (br == 1 ? b_o : b_u);
    ushort* out = h2br + (size_t)br * 3840 * 256;

    __shared__ ushort As[2][64 * 64];
    __shared__ ushort Bs[2][128 * 64];
    int t = threadIdx.x, lane = t & 63, wid = t >> 6;
    int wr = wid >> 1, wc = wid & 1;
    int m0 = xt * 64, n0 = yt * 128;
    const ushort* asrc = A + (size_t)m0 * 512;
    const ushort* bsrc = B + (size_t)n0 * 512;

    int ar = t >> 2, ac = (t & 3) * 16;
    bf16x8 qa0[2], qa1[2], qb0[4], qb1[4];

#define G2_ISSUE(PA, PB, KT)                                                              \
    {                                                                                     \
        const bf16x8* g = reinterpret_cast<const bf16x8*>(asrc + (size_t)ar * 512 + (KT) + ac); \
        PA[0] = g[0]; PA[1] = g[1];                                                       \
        _Pragma("unroll")                                                                 \
        for (int it = 0; it < 4; it++) {                                                  \
            int e = (it * 256 + t) * 8;                                                   \
            int rr = e >> 6, cc = e & 63;                                                 \
            PB[it] = *reinterpret_cast<const bf16x8*>(bsrc + (size_t)rr * 512 + (KT) + cc); \
        }                                                                                 \
    }
#define G2_COMMIT(PA, PB, BUF)                                                            \
    {                                                                                     \
        char* ab = reinterpret_cast<char*>(&As[BUF][0]);                                  \
        int off0 = (ar << 7) + ((ac << 1) ^ ((ar & 7) << 4));                             \
        int off1 = (ar << 7) + (((ac + 8) << 1) ^ ((ar & 7) << 4));                       \
        *reinterpret_cast<bf16x8*>(ab + off0) = PA[0];                                    \
        *reinterpret_cast<bf16x8*>(ab + off1) = PA[1];                                    \
        char* bb = reinterpret_cast<char*>(&Bs[BUF][0]);                                  \
        _Pragma("unroll")                                                                 \
        for (int it = 0; it < 4; it++) {                                                  \
            int e = (it * 256 + t) * 8;                                                   \
            int rr = e >> 6, cc = e & 63;                                                 \
            int off = (rr << 7) + ((cc << 1) ^ ((rr & 7) << 4));                          \
            *reinterpret_cast<bf16x8*>(bb + off) = PB[it];                                \
        }                                                                                 \
    }
#define G2_MFMA(BUF)                                                                      \
    _Pragma("unroll")                                                                     \
    for (int kk = 0; kk < 64; kk += 32) {                                                 \
        int cb = (kk + ((lane >> 4) << 3)) << 1;                                          \
        bf16x8 a[2], b[4];                                                                \
        _Pragma("unroll")                                                                 \
        for (int i = 0; i < 2; i++) a[i] = frag_ld(&As[BUF][0], wr * 32 + i * 16 + (lane & 15), cb); \
        _Pragma("unroll")                                                                 \
        for (int f = 0; f < 4; f++) b[f] = frag_ld(&Bs[BUF][0], wc * 64 + f * 16 + (lane & 15), cb); \
        _Pragma("unroll")                                                                 \
        for (int i = 0; i < 2; i++)                                                       \
            _Pragma("unroll")                                                             \
            for (int j = 0; j < 4; j++)                                                   \
                acc[i][j] = __builtin_amdgcn_mfma_f32_16x16x32_bf16(a[i], b[j], acc[i][j], 0, 0, 0); \
    }

    f32x4 acc[2][4] = {};
    G2_ISSUE(qa1, qb1, 0)
    G2_COMMIT(qa1, qb1, 0)
    G2_ISSUE(qa0, qb0, 64)
    __syncthreads();
    for (int kt = 0; kt < 512; kt += 128) {
        if (kt + 128 < 512) G2_ISSUE(qa1, qb1, kt + 128)
        G2_MFMA(0)
        if (kt + 64 < 512) G2_COMMIT(qa0, qb0, 1)
        __syncthreads();
        if (kt + 192 < 512) G2_ISSUE(qa0, qb0, kt + 192)
        G2_MFMA(1)
        if (kt + 128 < 512) G2_COMMIT(qa1, qb1, 0)
        __syncthreads();
    }
    int rb = m0 + wr * 32 + ((lane >> 4) << 2);
    int cb0 = n0 + wc * 64 + (lane & 15);
#pragma unroll
    for (int j = 0; j < 4; j++) {
        int col = cb0 + j * 16;
        float bv = bias[col];
#pragma unroll
        for (int i = 0; i < 2; i++)
#pragma unroll
            for (int q = 0; q < 4; q++) {
                int row = rb + i * 16 + q;
                float v = acc[i][j][q] + bv;
                v = v > 0.f ? v : 0.f;
                out[(size_t)row * 256 + col] = f2bf(v);
            }
    }
#undef G2_ISSUE
#undef G2_COMMIT
#undef G2_MFMA
}

// ---------------- appear = u - o - s -> hin[:,0:256); loc features -> hin[:,256:288)
__global__ void appear_pack(const ushort* __restrict__ h2br,
                            ushort* __restrict__ hin,
                            const float* __restrict__ boxes,
                            const float* __restrict__ im_info,
                            const int* __restrict__ o1, const int* __restrict__ o2,
                            const int* __restrict__ u, const int* __restrict__ im) {
    int i = blockIdx.x * 256 + threadIdx.x; // chunk over 3840*256/8
    if (i < N_PAIR * 32) {
        int p = i >> 5, ch = (i & 31) * 8;
        const ushort* ps = h2br + (size_t)p * 256 + ch;
        bf16x8 vs = *reinterpret_cast<const bf16x8*>(ps);
        bf16x8 vo = *reinterpret_cast<const bf16x8*>(ps + (size_t)3840 * 256);
        bf16x8 vu = *reinterpret_cast<const bf16x8*>(ps + (size_t)2 * 3840 * 256);
        union { bf16x8 v; ushort us[8]; } r;
#pragma unroll
        for (int j = 0; j < 8; j++)
            r.us[j] = f2bf(bf2f(((ushort)vu[j])) - bf2f(((ushort)vo[j])) - bf2f(((ushort)vs[j])));
        *reinterpret_cast<bf16x8*>(hin + (size_t)p * 288 + ch) = r.v;
    }
    if (blockIdx.x < 15) {
        int p = blockIdx.x * 256 + threadIdx.x;
        const float* sb = boxes + 5 * o1[p] + 1;
        const float* ob = boxes + 5 * o2[p] + 1;
        const float* ub = boxes + 5 * u[p] + 1;
        const float* ii = im_info + 3 * im[p];
        float hi = ii[0], wi = ii[1];
        float x_s = (sb[0] + sb[2]) * 0.5f, y_s = (sb[1] + sb[3]) * 0.5f;
        float w_s = sb[2] - sb[0], h_s = sb[3] - sb[1];
        float x_o = (ob[0] + ob[2]) * 0.5f, y_o = (ob[1] + ob[3]) * 0.5f;
        float w_o = ob[2] - ob[0], h_o = ob[3] - ob[1];
        float a_s = w_s * h_s, a_o = w_o * h_o;
        float a_u = (ub[2] - ub[0]) * (ub[3] - ub[1]);
        float area = wi * hi;
        float f[19];
        f[0] = x_s / wi;            f[1] = y_s / hi;
        f[2] = (x_s + w_s) / wi;    f[3] = (y_s + h_s) / hi;
        f[4] = a_s / area;
        f[5] = x_o / wi;            f[6] = y_o / hi;
        f[7] = (x_o + w_o) / wi;    f[8] = (y_o + h_o) / hi;
        f[9] = a_o / area;
        f[10] = (x_s - x_o) / w_o;  f[11] = (y_s - y_o) / h_o;
        f[12] = logf(w_s / w_o);    f[13] = logf(h_s / h_o);
        f[14] = (x_o - x_s) / w_s;  f[15] = (y_o - y_s) / h_s;
        f[16] = logf(w_o / w_s);    f[17] = logf(h_o / h_s);
        f[18] = a_u / area;
        ushort* row = hin + (size_t)p * 288 + 256;
#pragma unroll
        for (int k = 0; k < 19; k++) row[k] = f2bf(f[k]);
#pragma unroll
        for (int k = 19; k < 32; k++) row[k] = 0;
    }
}

// ---------------- GEMM3: h2 = relu(hin (3840x288) @ Wc1t + bc1) -> bf16 3840x256
// BM=64 BN=128 BK=32, pipelined (1-deep)
__global__ __launch_bounds__(256) void gemm3(const ushort* __restrict__ hin,
                                             const ushort* __restrict__ wc1t,
                                             const float* __restrict__ bc1,
                                             ushort* __restrict__ h2) {
    __shared__ ushort As[2][64 * 32];
    __shared__ ushort Bs[2][128 * 32];
    int t = threadIdx.x, lane = t & 63, wid = t >> 6;
    int wr = wid >> 1, wc = wid & 1;
    int m0 = blockIdx.x * 64, n0 = blockIdx.y * 128;
    const ushort* asrc = hin + (size_t)m0 * 288;
    const ushort* bsrc = wc1t + (size_t)n0 * 288;

    int ar = t >> 2, ac = (t & 3) * 8;
    bf16x8 pa, pb[2];
    auto issue = [&](int kt) {
        pa = *reinterpret_cast<const bf16x8*>(asrc + (size_t)ar * 288 + kt + ac);
#pragma unroll
        for (int it = 0; it < 2; it++) {
            int e = (it * 256 + t) * 8;
            int rr = e >> 5, cc = e & 31;
            pb[it] = *reinterpret_cast<const bf16x8*>(bsrc + (size_t)rr * 288 + kt + cc);
        }
    };
    auto commit = [&](int buf) {
        char* ab = reinterpret_cast<char*>(&As[buf][0]);
        int off0 = (ar << 6) + ((ac << 1) ^ ((ar & 3) << 4));
        *reinterpret_cast<bf16x8*>(ab + off0) = pa;
        char* bb = reinterpret_cast<char*>(&Bs[buf][0]);
#pragma unroll
        for (int it = 0; it < 2; it++) {
            int e = (it * 256 + t) * 8;
            int rr = e >> 5, cc = e & 31;
            int off = (rr << 6) + ((cc << 1) ^ ((rr & 3) << 4));
            *reinterpret_cast<bf16x8*>(bb + off) = pb[it];
        }
    };

    f32x4 acc[2][4] = {};
    issue(0);
    commit(0);
    __syncthreads();
    int cur = 0;
    for (int kt = 0; kt < 288; kt += 32) {
        int nxt = kt + 32;
        if (nxt < 288) issue(nxt);
        int cb = ((lane >> 4) << 3) << 1;
        bf16x8 a[2], b[4];
#pragma unroll
        for (int i = 0; i < 2; i++) a[i] = frag32_ld(&As[cur][0], wr * 32 + i * 16 + (lane & 15), cb);
#pragma unroll
        for (int f = 0; f < 4; f++) b[f] = frag32_ld(&Bs[cur][0], wc * 64 + f * 16 + (lane & 15), cb);
#pragma unroll
        for (int i = 0; i < 2; i++)
#pragma unroll
            for (int j = 0; j < 4; j++)
                acc[i][j] = __builtin_amdgcn_mfma_f32_16x16x32_bf16(a[i], b[j], acc[i][j], 0, 0, 0);
        if (nxt < 288) commit(cur ^ 1);
        __syncthreads();
        cur ^= 1;
    }
    int rb = m0 + wr * 32 + ((lane >> 4) << 2);
    int cb0 = n0 + wc * 64 + (lane & 15);
#pragma unroll
    for (int j = 0; j < 4; j++) {
        int col = cb0 + j * 16;
        float bv = bc1[col];
#pragma unroll
        for (int i = 0; i < 2; i++)
#pragma unroll
            for (int q = 0; q < 4; q++) {
                int row = rb + i * 16 + q;
                float v = acc[i][j][q] + bv;
                v = v > 0.f ? v : 0.f;
                h2[(size_t)row * 256 + col] = f2bf(v);
            }
    }
}

// ---------------- final: out = h2 (3840x256 bf16) @ Wc2 (256x3 f32) + bc2
__global__ void final_fc(const ushort* __restrict__ h2,
                         const float* __restrict__ wc2,
                         const float* __restrict__ bc2,
                         float* __restrict__ out) {
    __shared__ float w[768];
    int t = threadIdx.x;
    for (int i = t; i < 768; i += 256) w[i] = wc2[i];
    __syncthreads();
    int g = t >> 4, l = t & 15;
    int row = blockIdx.x * 16 + g;
    const ushort* hr = h2 + (size_t)row * 256 + l * 16;
    bf16x8 v0 = *reinterpret_cast<const bf16x8*>(hr);
    bf16x8 v1 = *reinterpret_cast<const bf16x8*>(hr + 8);
    float s0 = 0.f, s1 = 0.f, s2 = 0.f;
#pragma unroll
    for (int k = 0; k < 8; k++) {
        float h = bf2f((ushort)v0[k]);
        int c = (l * 16 + k) * 3;
        s0 += h * w[c]; s1 += h * w[c + 1]; s2 += h * w[c + 2];
    }
#pragma unroll
    for (int k = 0; k < 8; k++) {
        float h = bf2f((ushort)v1[k]);
        int c = (l * 16 + 8 + k) * 3;
        s0 += h * w[c]; s1 += h * w[c + 1]; s2 += h * w[c + 2];
    }
#pragma unroll
    for (int m = 1; m < 16; m <<= 1) {
        s0 += __shfl_xor(s0, m);
        s1 += __shfl_xor(s1, m);
        s2 += __shfl_xor(s2, m);
    }
    if (l == 0) {
        out[row * 3 + 0] = s0 + bc2[0];
        out[row * 3 + 1] = s1 + bc2[1];
        out[row * 3 + 2] = s2 + bc2[2];
    }
}

extern "C" void kernel_launch(void* const* d_in, const int* in_sizes, int n_in,
                              void* d_out, int out_size, void* d_ws, size_t ws_size,
                              hipStream_t stream) {
    (void)in_sizes; (void)n_in; (void)out_size; (void)ws_size;
    const float* xs = (const float*)d_in[0];
    const float* xo = (const float*)d_in[1];
    const float* xu = (const float*)d_in[2];
    const float* boxes = (const float*)d_in[3];
    const float* im_info = (const float*)d_in[4];
    const int* o1 = (const int*)d_in[5];
    const int* o2 = (const int*)d_in[6];
    const int* uu = (const int*)d_in[7];
    const int* im = (const int*)d_in[8];
    const float* Ws1 = (const float*)d_in[9];
    const float* bs1 = (const float*)d_in[10];
    const float* Ws2 = (const float*)d_in[11];
    const float* bs2 = (const float*)d_in[12];
    const float* Wo1 = (const float*)d_in[13];
    const float* bo1 = (const float*)d_in[14];
    const float* Wo2 = (const float*)d_in[15];
    const float* bo2 = (const float*)d_in[16];
    const float* Wu1 = (const float*)d_in[17];
    const float* bu1 = (const float*)d_in[18];
    const float* Wu2 = (const float*)d_in[19];
    const float* bu2 = (const float*)d_in[20];
    const float* Wc1 = (const float*)d_in[21];
    const float* bc1 = (const float*)d_in[22];
    const float* Wc2 = (const float*)d_in[23];
    const float* bc2 = (const float*)d_in[24];
    float* out = (float*)d_out;

    ushort* W1T = (ushort*)d_ws;                      // 3 * 512*2048 = 3,145,728
    ushort* H2BR = W1T;                               // alias (used after gemm1 is done with W1T)
    ushort* W2T = W1T + (size_t)3 * 512 * 2048;       // 3 * 256*512
    ushort* WC1T = W2T + (size_t)3 * 256 * 512;       // 256*288
    ushort* H1 = WC1T + (size_t)256 * 288;            // 3 * 3840*512
    ushort* HIN = H1 + (size_t)3 * 3840 * 512;        // 3840*288
    ushort* H2 = HIN + (size_t)3840 * 288;            // 3840*256

    transpose_convert<<<dim3(32, 8, 3), 256, 0, stream>>>(Ws1, Wo1, Wu1, W1T, 2048, 512, 2048);
    transpose_convert2<<<dim3(8, 4, 4), 256, 0, stream>>>(Ws2, Wo2, Wu2, Wc1, W2T, WC1T);
    gemm1<<<720, 256, 0, stream>>>(xs, xo, xu, W1T, bs1, bo1, bu1, H1);
    gemm2<<<360, 256, 0, stream>>>(H1, W2T, bs2, bo2, bu2, H2BR);
    appear_pack<<<480, 256, 0, stream>>>(H2BR, HIN, boxes, im_info, o1, o2, uu, im);
    gemm3<<<dim3(60, 2), 256, 0, stream>>>(HIN, WC1T, bc1, H2);
    final_fc<<<240, 256, 0, stream>>>(H2, Wc2, bc2, out);
}